// Round 13
// baseline (241.917 us; speedup 1.0000x reference)
//
#include <hip/hip_runtime.h>
#include <hip/hip_bf16.h>

typedef unsigned short u16;
typedef short bf16x8 __attribute__((ext_vector_type(8)));
typedef float f32x4 __attribute__((ext_vector_type(4)));

#define N_TOK 8192
#define DIM   1024
#define HID   2048
#define ADIM  128
#define SEQ   2048
#define LDP   2304   // row stride of hidP / WdQ (2048 + 256)

__device__ __forceinline__ u16 f2bf_bits(float f){
  unsigned u = __float_as_uint(f);
  unsigned r = (u + 0x7fffu + ((u >> 16) & 1u)) >> 16;
  return (u16)r;
}
__device__ __forceinline__ float bf2f(u16 v){ return __uint_as_float((unsigned)v << 16); }
__device__ __forceinline__ float siluf(float x){ return x / (1.f + __expf(-x)); }

__device__ __forceinline__ void gload16(const void* g, void* l){
  __builtin_amdgcn_global_load_lds((const __attribute__((address_space(1))) void*)g,
                                   (__attribute__((address_space(3))) void*)l, 16, 0, 0);
}

#define SB0() __builtin_amdgcn_sched_barrier(0)

// ================= 256^2 8-wave phased GEMM =================================
// r13 change vs r8: stages for BOTH kh half-tiles issued in P1 (kh0) and P3
// (kh1); P2/P4 issue none. Gate cover per half-tile rises 730->1100+ cyc
// (> HBM latency ~900), removing the 2 gate stalls/K-tile. Ledger: steady
// outstanding = 8 (P3 of kt-1 + P1 of kt); end-P2 vmcnt(4) drains P3-of-kt-1
// (= A1,B1 of kt, read next phase); end-P4 drains P1 (= A0',B0' of kt+1).
__global__ void __launch_bounds__(512, 2)
gemm_gu256(const u16* __restrict__ X, const u16* __restrict__ Wgu,
           const float* __restrict__ sumw, u16* __restrict__ hidP)
{
  extern __shared__ u16 lds[];
  const int tid = threadIdx.x, w = tid >> 6, lane = tid & 63;
  const int wm = w >> 2, wn = w & 3;
  const int xcd = blockIdx.x & 7, lloc = blockIdx.x >> 3;
  const int bm = (xcd >> 1) * 8 + (lloc & 7);
  const int bn = (xcd & 1) * 8 + (lloc >> 3);
  const long brow = (long)bm * 256, bcol = (long)bn * 256;
  const int frow = lane & 15;
  const int fks = ((lane >> 4) * 8) ^ (((lane >> 1) & 3) << 3);
  const int srow = lane >> 2;
  const int sslot = (((lane & 3) ^ ((lane >> 3) & 3)) * 8);

  f32x4 acc[8][4];
  #pragma unroll
  for (int m = 0; m < 8; m++)
    #pragma unroll
    for (int n = 0; n < 4; n++)
      #pragma unroll
      for (int i = 0; i < 4; i++) acc[m][n][i] = 0.f;

  auto stage = [&](const u16* __restrict__ gbase, long row0, int kt, int kh,
                   int p, int regoff) {
    #pragma unroll
    for (int i = 0; i < 2; i++) {
      const int r = (i * 8 + w) * 16 + srow;
      const u16* g = gbase + (row0 + r) * 1024 + kt * 64 + kh * 32 + sslot;
      u16* l = &lds[p * 32768 + regoff + kh * 8192 + (i * 8 + w) * 512];
      gload16(g, l);
    }
  };

#define AFRAG(mf, kss) (*(const bf16x8*)&lds[p*32768 + (kss)*8192 + (wm*128 + (mf)*16 + frow)*32 + fks])
#define BFRAG(nf, kss) (*(const bf16x8*)&lds[p*32768 + 16384 + (kss)*8192 + (wn*64 + (nf)*16 + frow)*32 + fks])

  stage(X, brow, 0, 0, 0, 0);
  stage(Wgu, bcol, 0, 0, 0, 16384);
  stage(X, brow, 0, 1, 0, 0);
  stage(Wgu, bcol, 0, 1, 0, 16384);
  asm volatile("s_waitcnt vmcnt(4)" ::: "memory");
  __builtin_amdgcn_s_barrier();

  for (int kt = 0; kt < 16; ++kt) {
    const int p = kt & 1, pn = p ^ 1;
    const int ktn = (kt < 15) ? kt + 1 : 15;
    bf16x8 b[4], a[4];

    // ---- P1: reads b(kh0) x4, a m0-3(kh0); stage A0' AND B0' (kt+1)
    a[0] = AFRAG(0, 0);
    b[0] = BFRAG(0, 0); b[1] = BFRAG(1, 0); b[2] = BFRAG(2, 0); b[3] = BFRAG(3, 0);
    SB0();
    a[1] = AFRAG(1, 0); SB0();
    a[2] = AFRAG(2, 0); SB0();
    a[3] = AFRAG(3, 0);
    stage(X, brow, ktn, 0, pn, 0);
    stage(Wgu, bcol, ktn, 0, pn, 16384);
    __builtin_amdgcn_s_barrier();
    asm volatile("s_waitcnt lgkmcnt(3)" ::: "memory"); SB0();
    __builtin_amdgcn_s_setprio(1);
    #pragma unroll
    for (int n = 0; n < 4; n++)
      acc[0][n] = __builtin_amdgcn_mfma_f32_16x16x32_bf16(a[0], b[n], acc[0][n], 0, 0, 0);
    asm volatile("s_waitcnt lgkmcnt(2)" ::: "memory"); SB0();
    #pragma unroll
    for (int n = 0; n < 4; n++)
      acc[1][n] = __builtin_amdgcn_mfma_f32_16x16x32_bf16(a[1], b[n], acc[1][n], 0, 0, 0);
    asm volatile("s_waitcnt lgkmcnt(1)" ::: "memory"); SB0();
    #pragma unroll
    for (int n = 0; n < 4; n++)
      acc[2][n] = __builtin_amdgcn_mfma_f32_16x16x32_bf16(a[2], b[n], acc[2][n], 0, 0, 0);
    asm volatile("s_waitcnt lgkmcnt(0)" ::: "memory"); SB0();
    #pragma unroll
    for (int n = 0; n < 4; n++)
      acc[3][n] = __builtin_amdgcn_mfma_f32_16x16x32_bf16(a[3], b[n], acc[3][n], 0, 0, 0);
    __builtin_amdgcn_s_setprio(0);
    __builtin_amdgcn_s_barrier();

    // ---- P2: reads a m4-7(kh0); no stage; end-gate (A1,B1 of kt)
    a[0] = AFRAG(4, 0); SB0();
    a[1] = AFRAG(5, 0); SB0();
    a[2] = AFRAG(6, 0); SB0();
    a[3] = AFRAG(7, 0);
    __builtin_amdgcn_s_barrier();
    asm volatile("s_waitcnt lgkmcnt(3)" ::: "memory"); SB0();
    __builtin_amdgcn_s_setprio(1);
    #pragma unroll
    for (int n = 0; n < 4; n++)
      acc[4][n] = __builtin_amdgcn_mfma_f32_16x16x32_bf16(a[0], b[n], acc[4][n], 0, 0, 0);
    asm volatile("s_waitcnt lgkmcnt(2)" ::: "memory"); SB0();
    #pragma unroll
    for (int n = 0; n < 4; n++)
      acc[5][n] = __builtin_amdgcn_mfma_f32_16x16x32_bf16(a[1], b[n], acc[5][n], 0, 0, 0);
    asm volatile("s_waitcnt lgkmcnt(1)" ::: "memory"); SB0();
    #pragma unroll
    for (int n = 0; n < 4; n++)
      acc[6][n] = __builtin_amdgcn_mfma_f32_16x16x32_bf16(a[2], b[n], acc[6][n], 0, 0, 0);
    asm volatile("s_waitcnt lgkmcnt(0)" ::: "memory"); SB0();
    #pragma unroll
    for (int n = 0; n < 4; n++)
      acc[7][n] = __builtin_amdgcn_mfma_f32_16x16x32_bf16(a[3], b[n], acc[7][n], 0, 0, 0);
    __builtin_amdgcn_s_setprio(0);
    asm volatile("s_waitcnt vmcnt(4)" ::: "memory");
    __builtin_amdgcn_s_barrier();

    // ---- P3: reads b(kh1) x4, a m0-3(kh1); stage A1' AND B1' (kt+1)
    a[0] = AFRAG(0, 1);
    b[0] = BFRAG(0, 1); b[1] = BFRAG(1, 1); b[2] = BFRAG(2, 1); b[3] = BFRAG(3, 1);
    SB0();
    a[1] = AFRAG(1, 1); SB0();
    a[2] = AFRAG(2, 1); SB0();
    a[3] = AFRAG(3, 1);
    stage(X, brow, ktn, 1, pn, 0);
    stage(Wgu, bcol, ktn, 1, pn, 16384);
    __builtin_amdgcn_s_barrier();
    asm volatile("s_waitcnt lgkmcnt(3)" ::: "memory"); SB0();
    __builtin_amdgcn_s_setprio(1);
    #pragma unroll
    for (int n = 0; n < 4; n++)
      acc[0][n] = __builtin_amdgcn_mfma_f32_16x16x32_bf16(a[0], b[n], acc[0][n], 0, 0, 0);
    asm volatile("s_waitcnt lgkmcnt(2)" ::: "memory"); SB0();
    #pragma unroll
    for (int n = 0; n < 4; n++)
      acc[1][n] = __builtin_amdgcn_mfma_f32_16x16x32_bf16(a[1], b[n], acc[1][n], 0, 0, 0);
    asm volatile("s_waitcnt lgkmcnt(1)" ::: "memory"); SB0();
    #pragma unroll
    for (int n = 0; n < 4; n++)
      acc[2][n] = __builtin_amdgcn_mfma_f32_16x16x32_bf16(a[2], b[n], acc[2][n], 0, 0, 0);
    asm volatile("s_waitcnt lgkmcnt(0)" ::: "memory"); SB0();
    #pragma unroll
    for (int n = 0; n < 4; n++)
      acc[3][n] = __builtin_amdgcn_mfma_f32_16x16x32_bf16(a[3], b[n], acc[3][n], 0, 0, 0);
    __builtin_amdgcn_s_setprio(0);
    __builtin_amdgcn_s_barrier();

    // ---- P4: reads a m4-7(kh1); no stage; end-gate (A0',B0' of kt+1)
    a[0] = AFRAG(4, 1); SB0();
    a[1] = AFRAG(5, 1); SB0();
    a[2] = AFRAG(6, 1); SB0();
    a[3] = AFRAG(7, 1);
    __builtin_amdgcn_s_barrier();
    asm volatile("s_waitcnt lgkmcnt(3)" ::: "memory"); SB0();
    __builtin_amdgcn_s_setprio(1);
    #pragma unroll
    for (int n = 0; n < 4; n++)
      acc[4][n] = __builtin_amdgcn_mfma_f32_16x16x32_bf16(a[0], b[n], acc[4][n], 0, 0, 0);
    asm volatile("s_waitcnt lgkmcnt(2)" ::: "memory"); SB0();
    #pragma unroll
    for (int n = 0; n < 4; n++)
      acc[5][n] = __builtin_amdgcn_mfma_f32_16x16x32_bf16(a[1], b[n], acc[5][n], 0, 0, 0);
    asm volatile("s_waitcnt lgkmcnt(1)" ::: "memory"); SB0();
    #pragma unroll
    for (int n = 0; n < 4; n++)
      acc[6][n] = __builtin_amdgcn_mfma_f32_16x16x32_bf16(a[2], b[n], acc[6][n], 0, 0, 0);
    asm volatile("s_waitcnt lgkmcnt(0)" ::: "memory"); SB0();
    #pragma unroll
    for (int n = 0; n < 4; n++)
      acc[7][n] = __builtin_amdgcn_mfma_f32_16x16x32_bf16(a[3], b[n], acc[7][n], 0, 0, 0);
    __builtin_amdgcn_s_setprio(0);
    asm volatile("s_waitcnt vmcnt(4)" ::: "memory");
    __builtin_amdgcn_s_barrier();
  }
#undef AFRAG
#undef BFRAG

  #pragma unroll
  for (int mf = 0; mf < 8; mf++)
    #pragma unroll
    for (int i = 0; i < 4; i++) {
      const long r = brow + wm * 128 + mf * 16 + (lane >> 4) * 4 + i;
      const float sw = sumw[r];
      #pragma unroll
      for (int q = 0; q < 2; q++) {
        const float g = acc[mf][2 * q][i], u = acc[mf][2 * q + 1][i];
        const int hcol = (bn * 8 + wn * 2 + q) * 16 + (lane & 15);
        hidP[r * LDP + hcol] = f2bf_bits(sw * (siluf(g) * u));
      }
    }
}

// ------------- shared 128^2 K-loop (BK=32, swizzled) ------------------------
__device__ __forceinline__ void kloop128(const u16* __restrict__ A, const u16* __restrict__ B,
                                         int lda, int ldb, int K,
                                         u16* lA, u16* lB, f32x4 (&acc)[4][4])
{
  const int tid = threadIdx.x, wave = tid >> 6, lane = tid & 63;
  const int wr = (wave >> 1) * 64, wc = (wave & 1) * 64;
  const int sr = tid >> 2, sks = ((tid & 3) ^ ((tid >> 3) & 3)) * 8;
  const u16* gA = A + (long)sr * lda + sks;
  const u16* gB = B + (long)sr * ldb + sks;
  const long rA = (long)64 * lda, rB = (long)64 * ldb;
  u16* lA0 = &lA[wave * 512]; u16* lA1 = &lA[2048 + wave * 512];
  u16* lB0 = &lB[wave * 512]; u16* lB1 = &lB[2048 + wave * 512];
  const int frow = lane & 15;
  const int fks = ((lane >> 4) * 8) ^ (((lane >> 1) & 3) << 3);

  for (int kt = 0; kt < K; kt += 32) {
    gload16(gA, lA0); gload16(gA + rA, lA1);
    gload16(gB, lB0); gload16(gB + rB, lB1);
    gA += 32; gB += 32;
    asm volatile("s_waitcnt vmcnt(0)" ::: "memory");
    __syncthreads();
    bf16x8 af[4], bfv[4];
    #pragma unroll
    for (int m = 0; m < 4; m++) af[m] = *(const bf16x8*)&lA[(wr + m * 16 + frow) * 32 + fks];
    #pragma unroll
    for (int n = 0; n < 4; n++) bfv[n] = *(const bf16x8*)&lB[(wc + n * 16 + frow) * 32 + fks];
    #pragma unroll
    for (int m = 0; m < 4; m++)
      #pragma unroll
      for (int n = 0; n < 4; n++)
        acc[m][n] = __builtin_amdgcn_mfma_f32_16x16x32_bf16(af[m], bfv[n], acc[m][n], 0, 0, 0);
    __syncthreads();
  }
}

__device__ __forceinline__ void acc_zero(f32x4 (&acc)[4][4]){
  #pragma unroll
  for (int m = 0; m < 4; m++)
    #pragma unroll
    for (int n = 0; n < 4; n++)
      #pragma unroll
      for (int i = 0; i < 4; i++) acc[m][n][i] = 0.f;
}

// ======== fused adapter v2: 16-row tiles, t=64, 2 blocks/CU =================
#define FB_AIN 0
#define FB_S   2048
#define FB_AO  3072
#define FB_AI  19456
__global__ void __launch_bounds__(256, 2)
fused_adapt(const u16* __restrict__ a_in, const u16* __restrict__ a_inT,
            const u16* __restrict__ a_out, const float* __restrict__ sumw,
            u16* __restrict__ hidP)
{
  extern __shared__ u16 lds[];
  const int tid = threadIdx.x, w = tid >> 6, lane = tid & 63;
  const int l15 = lane & 15, khi = lane >> 4;
  const int b = blockIdx.x >> 7, yt = blockIdx.x & 127;
  const int n0 = yt * 16;
  const u16* ain_b  = a_in  + (long)b * SEQ * ADIM;
  const u16* aout_b = a_out + (long)b * SEQ * ADIM;
  const u16* ainT_b = a_inT + (long)b * ADIM * SEQ;

  {
    int c = tid, row = c >> 4, slot = c & 15;
    gload16(ain_b + (long)(n0 + row) * ADIM + ((slot ^ (row & 7)) * 8),
            &lds[FB_AIN + c * 8]);
  }
  auto stage_tile = [&](int t0, int pb) {
    #pragma unroll
    for (int k = 0; k < 4; k++) {
      int c = tid + k * 256;
      int row = c >> 4, slot = c & 15;
      gload16(aout_b + (long)(t0 + row) * ADIM + ((slot ^ (row & 7)) * 8),
              &lds[FB_AO + pb * 8192 + c * 8]);
    }
    #pragma unroll
    for (int k = 0; k < 4; k++) {
      int c = tid + k * 256;
      int row = c >> 3, slot = c & 7;
      gload16(ainT_b + (long)row * SEQ + t0 + ((slot ^ (row & 7)) * 8),
              &lds[FB_AI + pb * 8192 + c * 8]);
    }
  };
  stage_tile(0, 0);

  f32x4 pacc[2];
  #pragma unroll
  for (int nf = 0; nf < 2; nf++)
    #pragma unroll
    for (int i = 0; i < 4; i++) pacc[nf][i] = 0.f;

#define LF256(base, row, kc) (*(const bf16x8*)&lds[(base) + (row)*128 + (((kc) ^ ((row)&7))*8)])
#define LF128(base, row, kc) (*(const bf16x8*)&lds[(base) + (row)*64  + (((kc) ^ ((row)&7))*8)])
#define MF(a_, b_, c_) __builtin_amdgcn_mfma_f32_16x16x32_bf16(a_, b_, c_, 0, 0, 0)

  for (int tt = 0; tt < 32; ++tt) {
    const int p = tt & 1;
    const int ttn = (tt < 31) ? tt + 1 : 31;
    stage_tile(ttn * 64, p ^ 1);
    asm volatile("s_waitcnt vmcnt(8)" ::: "memory");
    __syncthreads();

    f32x4 sacc;
    #pragma unroll
    for (int i = 0; i < 4; i++) sacc[i] = 0.f;
    const int AOb = FB_AO + p * 8192;
    #pragma unroll
    for (int ks = 0; ks < 4; ks++) {
      int kc = ks * 4 + khi;
      bf16x8 av = LF256(FB_AIN, l15, kc);
      bf16x8 bv = LF256(AOb, w * 16 + l15, kc);
      sacc = MF(av, bv, sacc);
    }
    #pragma unroll
    for (int i = 0; i < 4; i++) {
      int row = khi * 4 + i;
      int col = w * 16 + l15;
      float v = fminf(5.f, fmaxf(-5.f, sacc[i]));
      lds[FB_S + row * 64 + (((col >> 3) ^ (row & 7)) * 8) + (col & 7)] =
          f2bf_bits(siluf(v));
    }
    __syncthreads();
    const int AIb = FB_AI + p * 8192;
    #pragma unroll
    for (int ks = 0; ks < 2; ks++) {
      int kc = ks * 4 + khi;
      bf16x8 av = LF128(FB_S, l15, kc);
      #pragma unroll
      for (int nf = 0; nf < 2; nf++) {
        bf16x8 bv = LF128(AIb, w * 32 + nf * 16 + l15, kc);
        pacc[nf] = MF(av, bv, pacc[nf]);
      }
    }
    __syncthreads();
  }
#undef LF256
#undef LF128
#undef MF

  const long nb = (long)b * SEQ + n0;
  #pragma unroll
  for (int nf = 0; nf < 2; nf++)
    #pragma unroll
    for (int i = 0; i < 4; i++) {
      long n = nb + khi * 4 + i;
      int c = w * 32 + nf * 16 + l15;
      hidP[n * LDP + 2048 + c] = f2bf_bits(0.1f * sumw[n] * pacc[nf][i]);
    }
}

// ------ merged: pre-split (blk<256) | M1/M2-split (blk 256-319) -------------
__global__ void __launch_bounds__(256, 2)
split_pq(const u16* __restrict__ xb, const u16* __restrict__ Wpreb,
         const u16* __restrict__ WdQ, const u16* __restrict__ WaTb,
         const u16* __restrict__ Wob, const u16* __restrict__ WeTb,
         float* __restrict__ part, float* __restrict__ qpart)
{
  __shared__ u16 lA[4096];
  __shared__ u16 lB[4096];
  const int blk = blockIdx.x;
  const int wave = threadIdx.x >> 6, lane = threadIdx.x & 63;
  f32x4 acc[4][4]; acc_zero(acc);
  const int wr = (wave >> 1) * 64, wc = (wave & 1) * 64;

  if (blk < 256) {
    const int y = blk & 63, z = blk >> 6;
    const long brow = (long)y * 128;
    const u16* A = xb + brow * DIM + (long)z * 256;
    const u16* B = Wpreb + (long)z * 256;
    kloop128(A, B, DIM, DIM, 256, lA, lB, acc);
    float* po = part + (long)z * (N_TOK * ADIM);
    const long rr = brow + wr + ((lane >> 4) << 2);
    const int cc = wc + (lane & 15);
    #pragma unroll
    for (int m = 0; m < 4; m++)
      #pragma unroll
      for (int i = 0; i < 4; i++) {
        long r = rr + m * 16 + i;
        #pragma unroll
        for (int n = 0; n < 4; n++)
          po[r * 128 + cc + n * 16] = acc[m][n][i];
      }
  } else {
    const int q = blk - 256;
    const int y = q & 7, z = q >> 3;
    const int sel = z >> 2, split = z & 3;
    const long brow = (long)y * 128;
    const int lda = sel ? HID : LDP;
    const u16* A = (sel ? Wob : WdQ) + brow * lda + (long)split * 512;
    const u16* B = (sel ? WeTb : WaTb) + (long)split * 512;
    kloop128(A, B, lda, HID, 512, lA, lB, acc);
    float* po = qpart + (long)z * 131072;
    const long rr = brow + wr + ((lane >> 4) << 2);
    const int cc = wc + (lane & 15);
    #pragma unroll
    for (int m = 0; m < 4; m++)
      #pragma unroll
      for (int i = 0; i < 4; i++) {
        long r = rr + m * 16 + i;
        #pragma unroll
        for (int n = 0; n < 4; n++)
          po[r * 128 + cc + n * 16] = acc[m][n][i];
      }
  }
}

// ------ merged: he-GEMM (blk<512) | postf-split (blk 512-767) ---------------
__global__ void __launch_bounds__(256, 2)
he_postf(const u16* __restrict__ preb, const u16* __restrict__ Weadb,
         u16* __restrict__ heb, const u16* __restrict__ hidP,
         const u16* __restrict__ Wpostb, float* __restrict__ postfp)
{
  __shared__ u16 lA[4096];
  __shared__ u16 lB[4096];
  const int blk = blockIdx.x;
  const int wave = threadIdx.x >> 6, lane = threadIdx.x & 63;
  f32x4 acc[4][4]; acc_zero(acc);
  const int wr = (wave >> 1) * 64, wc = (wave & 1) * 64;

  if (blk < 512) {
    const int y = blk & 63, e = blk >> 6;
    const long brow = (long)y * 128;
    const u16* A = preb + brow * ADIM;
    const u16* B = Weadb + (long)e * ADIM * ADIM;
    kloop128(A, B, ADIM, ADIM, ADIM, lA, lB, acc);
    u16* O = heb + (long)e * N_TOK * ADIM;
    const long r0 = brow + wr + ((lane >> 4) << 2);
    const long c0 = wc + (lane & 15);
    #pragma unroll
    for (int m = 0; m < 4; m++)
      #pragma unroll
      for (int i = 0; i < 4; i++) {
        long r = r0 + m * 16 + i;
        #pragma unroll
        for (int n = 0; n < 4; n++)
          O[r * ADIM + c0 + n * 16] = f2bf_bits(acc[m][n][i]);
      }
  } else {
    const int q = blk - 512;
    const int y = q & 63, z = q >> 6;
    const long brow = (long)y * 128;
    const u16* A = hidP + brow * LDP + (long)z * 512;
    const u16* B = Wpostb + (long)z * 512;
    kloop128(A, B, LDP, HID, 512, lA, lB, acc);
    float* po = postfp + (long)z * (N_TOK * ADIM);
    const long rr = brow + wr + ((lane >> 4) << 2);
    const int cc = wc + (lane & 15);
    #pragma unroll
    for (int m = 0; m < 4; m++)
      #pragma unroll
      for (int i = 0; i < 4; i++) {
        long r = rr + m * 16 + i;
        #pragma unroll
        for (int n = 0; n < 4; n++)
          po[r * 128 + cc + n * 16] = acc[m][n][i];
      }
  }
}

// ------- out = hidP @ WdQ^T (K=2304) + loss; XCD row-group swizzle ----------
__global__ void __launch_bounds__(256, 2)
gemm_f32(const u16* __restrict__ Ag, const u16* __restrict__ Bg,
         const float* __restrict__ stats, float* __restrict__ out)
{
  __shared__ u16 lA[4096];
  __shared__ u16 lB[4096];
  const int wave = threadIdx.x >> 6, lane = threadIdx.x & 63;
  const int id = blockIdx.x;
  const int xcd = id & 7, k = id >> 3;
  const long brow = (long)(xcd * 8 + (k & 7)) * 128;
  const long bcol = (long)(k >> 3) * 128;
  f32x4 acc[4][4]; acc_zero(acc);
  kloop128(Ag + brow * LDP, Bg + bcol * LDP, LDP, LDP, LDP, lA, lB, acc);
  const int wr = (wave >> 1) * 64, wc = (wave & 1) * 64;
  const long r0 = brow + wr + ((lane >> 4) << 2);
  const long c0 = bcol + wc + (lane & 15);
  #pragma unroll
  for (int m = 0; m < 4; m++)
    #pragma unroll
    for (int i = 0; i < 4; i++) {
      long r = r0 + m * 16 + i;
      #pragma unroll
      for (int n = 0; n < 4; n++)
        out[r * DIM + c0 + n * 16] = acc[m][n][i];
    }
  if (id == 0 && threadIdx.x == 0) {
    float tot = 0;
    #pragma unroll
    for (int e = 0; e < 8; e++) tot += stats[e];
    float target = tot * 0.125f;
    float lb = 0;
    #pragma unroll
    for (int e = 0; e < 8; e++) { float d = stats[e] - target; lb += d * d; }
    lb *= 0.125f;
    float z = stats[8] * (1.f / (8192.f * 2.f)) + stats[9] * (1.f / (8192.f * 4.f));
    out[(size_t)N_TOK * DIM] = 0.001f * (lb + z);
  }
}

// ======== merged prep: router | wprep | cvt_t2 ==============================
__global__ void __launch_bounds__(256)
prep_all(const float* __restrict__ x, const float* __restrict__ Wrg,
         const float* __restrict__ Wre, float* __restrict__ sumw,
         float* __restrict__ fwv, int* __restrict__ eidxv,
         float* __restrict__ stats, u16* __restrict__ xb,
         const float* __restrict__ Wg, const float* __restrict__ Wu,
         const float* __restrict__ Wd, const float* __restrict__ Wo,
         const float* __restrict__ Wpost, const float* __restrict__ Wpre,
         const float* __restrict__ Wead,
         u16* __restrict__ Wgu, u16* __restrict__ WdQ,
         u16* __restrict__ Wob, u16* __restrict__ Wpostb,
         u16* __restrict__ Wpreb, u16* __restrict__ Weadb,
         const float* __restrict__ Wa, const float* __restrict__ We,
         u16* __restrict__ Ta, u16* __restrict__ Te)
{
  __shared__ float lst[10];
  const int blk = blockIdx.x;
  if (blk < 512) {
    if (threadIdx.x < 10) lst[threadIdx.x] = 0.f;
    __syncthreads();
    const int wave = threadIdx.x >> 6, lane = threadIdx.x & 63;
    const float4* wg0 = (const float4*)Wrg;
    const float4* wg1 = (const float4*)(Wrg + 1024);
    const float4* we0 = (const float4*)Wre;
    const float4* we1 = (const float4*)(Wre + 1024);
    const float4* we2 = (const float4*)(Wre + 2048);
    const float4* we3 = (const float4*)(Wre + 3072);
    for (int t = 0; t < 4; t++) {
      const long n = (long)blk * 16 + wave * 4 + t;
      const float4* xr = (const float4*)(x + n * 1024);
      float d0 = 0, d1 = 0, t0 = 0, t1 = 0, t2 = 0, t3 = 0;
      #pragma unroll
      for (int j = 0; j < 4; j++) {
        int id = j * 64 + lane;
        float4 xv = xr[id];
        ushort4 xc;
        xc.x = f2bf_bits(xv.x); xc.y = f2bf_bits(xv.y);
        xc.z = f2bf_bits(xv.z); xc.w = f2bf_bits(xv.w);
        *(ushort4*)(xb + n * 1024 + id * 4) = xc;
        float4 a;
        a = wg0[id]; d0 += xv.x * a.x + xv.y * a.y + xv.z * a.z + xv.w * a.w;
        a = wg1[id]; d1 += xv.x * a.x + xv.y * a.y + xv.z * a.z + xv.w * a.w;
        a = we0[id]; t0 += xv.x * a.x + xv.y * a.y + xv.z * a.z + xv.w * a.w;
        a = we1[id]; t1 += xv.x * a.x + xv.y * a.y + xv.z * a.z + xv.w * a.w;
        a = we2[id]; t2 += xv.x * a.x + xv.y * a.y + xv.z * a.z + xv.w * a.w;
        a = we3[id]; t3 += xv.x * a.x + xv.y * a.y + xv.z * a.z + xv.w * a.w;
      }
      #pragma unroll
      for (int o = 32; o; o >>= 1) {
        d0 += __shfl_xor(d0, o); d1 += __shfl_xor(d1, o);
        t0 += __shfl_xor(t0, o); t1 += __shfl_xor(t1, o);
        t2 += __shfl_xor(t2, o); t3 += __shfl_xor(t3, o);
      }
      if (lane == 0) {
        float mg = fmaxf(d0, d1);
        float e0 = __expf(d0 - mg), e1 = __expf(d1 - mg);
        float invg = 1.f / (e0 + e1);
        float p0 = e0 * invg, p1 = e1 * invg;
        int gi = (d1 > d0) ? 1 : 0;
        float gw = fmaxf(p0, p1);
        float l[4] = {t0, t1, t2, t3};
        float ml = fmaxf(fmaxf(l[0], l[1]), fmaxf(l[2], l[3]));
        float p[4]; float su = 0;
        #pragma unroll
        for (int i = 0; i < 4; i++) { p[i] = __expf(l[i] - ml); su += p[i]; }
        float isu = 1.f / su;
        #pragma unroll
        for (int i = 0; i < 4; i++) p[i] *= isu;
        int i1 = 0;
        #pragma unroll
        for (int i = 1; i < 4; i++) if (p[i] > p[i1]) i1 = i;
        int i2 = (i1 == 0) ? 1 : 0;
        #pragma unroll
        for (int i = 0; i < 4; i++) if (i != i1 && p[i] > p[i2]) i2 = i;
        float s2 = p[i1] + p[i2];
        float invs = 1.f / (s2 + 1e-7f);
        float f1 = gw * p[i1] * invs, f2 = gw * p[i2] * invs;
        int ea = gi * 4 + i1, eb = gi * 4 + i2;
        sumw[n] = f1 + f2;
        fwv[2 * n] = f1; fwv[2 * n + 1] = f2;
        eidxv[2 * n] = ea; eidxv[2 * n + 1] = eb;
        atomicAdd(&lst[ea], f1);
        atomicAdd(&lst[eb], f2);
        atomicAdd(&lst[8], d0 * d0 + d1 * d1);
        atomicAdd(&lst[9], t0 * t0 + t1 * t1 + t2 * t2 + t3 * t3);
      }
    }
    __syncthreads();
    if (threadIdx.x < 10) atomicAdd(&stats[threadIdx.x], lst[threadIdx.x]);
  } else if (blk < 4864) {
    long i = ((long)(blk - 512) * 256 + threadIdx.x) * 8;
    const float* s; u16* d; long so, doff;
    if (i < 4194304) {
      long rp = i >> 10, c = i & 1023;
      long i32 = rp >> 5, wi = rp & 31;
      s = (wi < 16) ? Wg : Wu;
      so = (i32 * 16 + (wi & 15)) * 1024 + c;
      d = Wgu; doff = i;
    } else if (i < 6291456) {
      long j = i - 4194304;
      long r = j >> 11, c = j & 2047;
      s = Wd; so = j;
      d = WdQ; doff = r * LDP + c;
    } else if (i < 8388608) { s = Wo;    so = i - 6291456; d = Wob;    doff = so; }
    else if (i < 8650752)   { s = Wpost; so = i - 8388608; d = Wpostb; doff = so; }
    else if (i < 8781824)   { s = Wpre;  so = i - 8650752; d = Wpreb;  doff = so; }
    else                    { s = Wead;  so = i - 8781824; d = Weadb;  doff = so; }
    float4 v0 = *(const float4*)(s + so), v1 = *(const float4*)(s + so + 4);
    ushort4 p, q;
    p.x = f2bf_bits(v0.x); p.y = f2bf_bits(v0.y); p.z = f2bf_bits(v0.z); p.w = f2bf_bits(v0.w);
    q.x = f2bf_bits(v1.x); q.y = f2bf_bits(v1.y); q.z = f2bf_bits(v1.z); q.w = f2bf_bits(v1.w);
    *(ushort4*)(d + doff) = p;
    *(ushort4*)(d + doff + 4) = q;
  } else {
    int bid = blk - 4864;
    const float* src = (bid < 1024) ? Wa : We;
    u16* dst = (bid < 1024) ? Ta : Te;
    int idx = (bid & 1023) * 256 + threadIdx.x;
    int c = idx >> 11, r = idx & 2047;
    dst[idx] = f2bf_bits(src[(long)r * 128 + c]);
  }
}

// ------ merged: ln_rows(pre) (blk<2048) | reduce_q (blk 2048-3071) ----------
__global__ void __launch_bounds__(256)
ln1_rq(const float* __restrict__ part, const float* __restrict__ qpart,
       const float* __restrict__ g, const float* __restrict__ b,
       u16* __restrict__ a_in, u16* __restrict__ a_inT, u16* __restrict__ preb,
       u16* __restrict__ WdQ)
{
  const int blk = blockIdx.x;
  if (blk < 2048) {
    int wave = threadIdx.x >> 6, lane = threadIdx.x & 63;
    long n = (long)blk * 4 + wave;
    long base = n * 128;
    float x0 = 0.f, x1 = 0.f;
    #pragma unroll
    for (int s = 0; s < 4; s++) {
      x0 += part[(long)s * (N_TOK * ADIM) + base + lane];
      x1 += part[(long)s * (N_TOK * ADIM) + base + 64 + lane];
    }
    float s2 = x0 + x1, q = x0 * x0 + x1 * x1;
    #pragma unroll
    for (int o = 32; o; o >>= 1) { s2 += __shfl_xor(s2, o); q += __shfl_xor(q, o); }
    float m = s2 * (1.f / 128.f);
    float var = q * (1.f / 128.f) - m * m;
    float inv = rsqrtf(var + 1e-5f);
    float y0 = (x0 - m) * inv * g[lane] + b[lane];
    float y1 = (x1 - m) * inv * g[lane + 64] + b[lane + 64];
    a_in[base + lane] = f2bf_bits(y0);
    a_in[base + 64 + lane] = f2bf_bits(y1);
    long bb = n >> 11, ss = n & 2047;
    a_inT[(bb * 128 + lane) * 2048 + ss] = f2bf_bits(y0);
    a_inT[(bb * 128 + lane + 64) * 2048 + ss] = f2bf_bits(y1);
    preb[base + lane] = f2bf_bits(x0);
    preb[base + 64 + lane] = f2bf_bits(x1);
  } else {
    int idx = (blk - 2048) * 256 + threadIdx.x;
    int r = idx >> 8, c = idx & 255;
    const float* p = qpart + ((c < 128) ? 0 : 524288) + (long)r * 128 + (c & 127);
    float a = p[0] + p[131072] + p[262144] + p[393216];
    WdQ[(long)r * LDP + 2048 + c] = f2bf_bits(a);
  }
}

// ------ merged: ln_combine (blk<2048) | ln_rows(postf) (blk 2048-4095) ------
__global__ void __launch_bounds__(256)
lnc_ln2(const u16* __restrict__ heb, const int* __restrict__ eidxv,
        const float* __restrict__ fwv, const float* __restrict__ g_e,
        const float* __restrict__ b_e, u16* __restrict__ hidP,
        const float* __restrict__ postfp, const float* __restrict__ g_an,
        const float* __restrict__ b_an, const float* __restrict__ sumw,
        u16* __restrict__ a_out)
{
  const int blk = blockIdx.x;
  const int wave = threadIdx.x >> 6, lane = threadIdx.x & 63;
  if (blk < 2048) {
    const long n = (long)blk * 4 + wave;
    float o0 = 0.f, o1 = 0.f;
    #pragma unroll
    for (int k = 0; k < 2; k++) {
      const int e = eidxv[2 * n + k];
      const float w = fwv[2 * n + k];
      const u16* row = heb + ((long)e * N_TOK + n) * 128;
      float h0 = bf2f(row[lane]), h1 = bf2f(row[lane + 64]);
      float s = h0 + h1, q = h0 * h0 + h1 * h1;
      #pragma unroll
      for (int o = 32; o; o >>= 1) { s += __shfl_xor(s, o); q += __shfl_xor(q, o); }
      float m = s * (1.f / 128.f);
      float var = q * (1.f / 128.f) - m * m;
      float inv = rsqrtf(var + 1e-5f);
      o0 += w * ((h0 - m) * inv * g_e[e * 128 + lane] + b_e[e * 128 + lane]);
      o1 += w * ((h1 - m) * inv * g_e[e * 128 + lane + 64] + b_e[e * 128 + lane + 64]);
    }
    hidP[n * LDP + 2176 + lane] = f2bf_bits(0.1f * o0);
    hidP[n * LDP + 2176 + 64 + lane] = f2bf_bits(0.1f * o1);
  } else {
    long n = (long)(blk - 2048) * 4 + wave;
    long base = n * 128;
    float x0 = 0.f, x1 = 0.f;
    #pragma unroll
    for (int s = 0; s < 4; s++) {
      x0 += postfp[(long)s * (N_TOK * ADIM) + base + lane];
      x1 += postfp[(long)s * (N_TOK * ADIM) + base + 64 + lane];
    }
    float invw = 1.f / sumw[n]; x0 *= invw; x1 *= invw;
    float s2 = x0 + x1, q = x0 * x0 + x1 * x1;
    #pragma unroll
    for (int o = 32; o; o >>= 1) { s2 += __shfl_xor(s2, o); q += __shfl_xor(q, o); }
    float m = s2 * (1.f / 128.f);
    float var = q * (1.f / 128.f) - m * m;
    float inv = rsqrtf(var + 1e-5f);
    a_out[base + lane] = f2bf_bits((x0 - m) * inv * g_an[lane] + b_an[lane]);
    a_out[base + 64 + lane] = f2bf_bits((x1 - m) * inv * g_an[lane + 64] + b_an[lane + 64]);
  }
}

// ----------------------------------------------------------------------------
extern "C" void kernel_launch(void* const* d_in, const int* in_sizes, int n_in,
                              void* d_out, int out_size, void* d_ws, size_t ws_size,
                              hipStream_t stream)
{
  (void)in_sizes; (void)n_in; (void)out_size; (void)ws_size;
  const float* x       = (const float*)d_in[0];
  const float* W_up    = (const float*)d_in[1];
  const float* W_gate  = (const float*)d_in[2];
  const float* W_down  = (const float*)d_in[3];
  const float* W_pre   = (const float*)d_in[4];
  const float* W_post  = (const float*)d_in[5];
  const float* g_an    = (const float*)d_in[6];
  const float* b_an    = (const float*)d_in[7];
  const float* W_aproj = (const float*)d_in[8];
  const float* W_ead   = (const float*)d_in[9];
  const float* g_e     = (const float*)d_in[10];
  const float* b_e     = (const float*)d_in[11];
  const float* W_eproj = (const float*)d_in[12];
  const float* W_oproj = (const float*)d_in[13];
  const float* W_rg    = (const float*)d_in[14];
  const float* W_re    = (const float*)d_in[15];
  float* out = (float*)d_out;

  char* base = (char*)d_ws; size_t off = 0;
  auto alloc = [&](size_t bytes) -> void* {
    void* p = base + off; off = (off + bytes + 255) & ~(size_t)255; return p;
  };
  u16*   xb     = (u16*)  alloc((size_t)N_TOK * DIM * 2);
  u16*   Wgu    = (u16*)  alloc((size_t)2 * HID * DIM * 2);       // packed gate|up
  u16*   WdQ    = (u16*)  alloc((size_t)DIM * LDP * 2);           // Wd | M2 | M1
  u16*   Wob    = (u16*)  alloc((size_t)DIM * HID * 2);
  u16*   Wpostb = (u16*)  alloc((size_t)ADIM * HID * 2);
  u16*   Wpreb  = (u16*)  alloc((size_t)ADIM * DIM * 2);
  u16*   WaTb   = (u16*)  alloc((size_t)ADIM * HID * 2);
  u16*   WeTb   = (u16*)  alloc((size_t)ADIM * HID * 2);
  u16*   Weadb  = (u16*)  alloc((size_t)8 * ADIM * ADIM * 2);
  u16*   hidP   = (u16*)  alloc((size_t)N_TOK * LDP * 2);         // scaled hid | P
  u16*   heb    = (u16*)  alloc((size_t)8 * N_TOK * ADIM * 2);    // also part arena
  float* part   = (float*)heb;
  u16*   preb   = (u16*)  alloc((size_t)N_TOK * ADIM * 2);
  u16*   a_in   = (u16*)  alloc((size_t)N_TOK * ADIM * 2);
  u16*   a_inT  = (u16*)  alloc((size_t)N_TOK * ADIM * 2);
  u16*   a_out  = (u16*)  alloc((size_t)N_TOK * ADIM * 2);
  float* sumw   = (float*)alloc((size_t)N_TOK * 4);
  float* fwv    = (float*)alloc((size_t)N_TOK * 2 * 4);
  int*   eidxv  = (int*)  alloc((size_t)N_TOK * 2 * 4);
  float* stats  = (float*)alloc(64);
  // d_out (33.5 MB) time-shared as scratch, all strictly before gemm_f32:
  //  - postfp (16.8 MB f32 postf partials): he_postf -> lnc_ln2
  //  - qpart  (4.2 MB f32 M1/M2 partials, at +16.8MB): split_pq -> ln1_rq
  float* postfp = (float*)d_out;
  float* qpart  = (float*)((char*)d_out + 16777216);

  hipFuncSetAttribute((const void*)gemm_gu256,
                      hipFuncAttributeMaxDynamicSharedMemorySize, 131072);
  hipFuncSetAttribute((const void*)fused_adapt,
                      hipFuncAttributeMaxDynamicSharedMemorySize, 71680);

  hipMemsetAsync(stats, 0, 64, stream);

  // 1. router | weight-pack | transposes
  prep_all<<<6912, 256, 0, stream>>>(x, W_rg, W_re, sumw, fwv, eidxv, stats, xb,
                                     W_gate, W_up, W_down, W_oproj, W_post, W_pre,
                                     W_ead, Wgu, WdQ, Wob, Wpostb, Wpreb, Weadb,
                                     W_aproj, W_eproj, WaTb, WeTb);

  // 2. hidP[:, :2048] = sumw * silu(x@Wg^T) * (x@Wu^T)
  gemm_gu256<<<512, 512, 131072, stream>>>(xb, Wgu, sumw, hidP);

  // 3. pre-split (part) | M1/M2-split (qpart)
  split_pq<<<320, 256, 0, stream>>>(xb, Wpreb, WdQ, WaTb, Wob, WeTb, part, qpart);

  // 4. LN(pre) -> a_in/a_inT/preb | reduce qpart -> WdQ Q-cols
  ln1_rq<<<3072, 256, 0, stream>>>(part, qpart, g_an, b_an, a_in, a_inT, preb, WdQ);

  // 5. he[e] = preb @ Wead[e]^T -> heb | postf-split -> postfp
  he_postf<<<768, 256, 0, stream>>>(preb, Weadb, heb, hidP, Wpostb, postfp);

  // 6. expert LN+combine -> hidP[:,2176:] | LN(postf/sumw) -> a_out
  lnc_ln2<<<4096, 256, 0, stream>>>(heb, eidxv, fwv, g_e, b_e, hidP,
                                    postfp, g_an, b_an, sumw, a_out);

  // 7. fused adapter: hidP[:,2048:2176] = 0.1*sumw*(silu(a_in@a_out^T)@a_in)
  fused_adapt<<<512, 256, 71680, stream>>>(a_in, a_inT, a_out, sumw, hidP);

  // 8. out = hidP @ WdQ^T (K=2304) + router loss
  gemm_f32<<<512, 256, 0, stream>>>(hidP, WdQ, stats, out);
}

// Round 14
// 240.463 us; speedup vs baseline: 1.0060x; 1.0060x over previous
//
#include <hip/hip_runtime.h>
#include <hip/hip_bf16.h>

typedef unsigned short u16;
typedef short bf16x8 __attribute__((ext_vector_type(8)));
typedef float f32x4 __attribute__((ext_vector_type(4)));

#define N_TOK 8192
#define DIM   1024
#define HID   2048
#define ADIM  128
#define SEQ   2048
#define LDP   2304   // row stride of hidP / WdQ (2048 + 256)

__device__ __forceinline__ u16 f2bf_bits(float f){
  unsigned u = __float_as_uint(f);
  unsigned r = (u + 0x7fffu + ((u >> 16) & 1u)) >> 16;
  return (u16)r;
}
__device__ __forceinline__ float bf2f(u16 v){ return __uint_as_float((unsigned)v << 16); }
__device__ __forceinline__ float siluf(float x){ return x / (1.f + __expf(-x)); }

__device__ __forceinline__ void gload16(const void* g, void* l){
  __builtin_amdgcn_global_load_lds((const __attribute__((address_space(1))) void*)g,
                                   (__attribute__((address_space(3))) void*)l, 16, 0, 0);
}

#define SB0() __builtin_amdgcn_sched_barrier(0)

// ================= 256^2 8-wave phased GEMM (r8 variant: best measured) =====
__global__ void __launch_bounds__(512, 2)
gemm_gu256(const u16* __restrict__ X, const u16* __restrict__ Wgu,
           const float* __restrict__ sumw, u16* __restrict__ hidP)
{
  extern __shared__ u16 lds[];
  const int tid = threadIdx.x, w = tid >> 6, lane = tid & 63;
  const int wm = w >> 2, wn = w & 3;
  const int xcd = blockIdx.x & 7, lloc = blockIdx.x >> 3;
  const int bm = (xcd >> 1) * 8 + (lloc & 7);
  const int bn = (xcd & 1) * 8 + (lloc >> 3);
  const long brow = (long)bm * 256, bcol = (long)bn * 256;
  const int frow = lane & 15;
  const int fks = ((lane >> 4) * 8) ^ (((lane >> 1) & 3) << 3);
  const int srow = lane >> 2;
  const int sslot = (((lane & 3) ^ ((lane >> 3) & 3)) * 8);

  f32x4 acc[8][4];
  #pragma unroll
  for (int m = 0; m < 8; m++)
    #pragma unroll
    for (int n = 0; n < 4; n++)
      #pragma unroll
      for (int i = 0; i < 4; i++) acc[m][n][i] = 0.f;

  auto stage = [&](const u16* __restrict__ gbase, long row0, int kt, int kh,
                   int p, int regoff) {
    #pragma unroll
    for (int i = 0; i < 2; i++) {
      const int r = (i * 8 + w) * 16 + srow;
      const u16* g = gbase + (row0 + r) * 1024 + kt * 64 + kh * 32 + sslot;
      u16* l = &lds[p * 32768 + regoff + kh * 8192 + (i * 8 + w) * 512];
      gload16(g, l);
    }
  };

#define AFRAG(mf, kss) (*(const bf16x8*)&lds[p*32768 + (kss)*8192 + (wm*128 + (mf)*16 + frow)*32 + fks])
#define BFRAG(nf, kss) (*(const bf16x8*)&lds[p*32768 + 16384 + (kss)*8192 + (wn*64 + (nf)*16 + frow)*32 + fks])

  stage(X, brow, 0, 0, 0, 0);
  stage(Wgu, bcol, 0, 0, 0, 16384);
  stage(X, brow, 0, 1, 0, 0);
  stage(Wgu, bcol, 0, 1, 0, 16384);
  asm volatile("s_waitcnt vmcnt(4)" ::: "memory");
  __builtin_amdgcn_s_barrier();

  for (int kt = 0; kt < 16; ++kt) {
    const int p = kt & 1, pn = p ^ 1;
    const int ktn = (kt < 15) ? kt + 1 : 15;
    bf16x8 b[4], a[4];

    // ---- P1
    a[0] = AFRAG(0, 0);
    b[0] = BFRAG(0, 0); b[1] = BFRAG(1, 0); b[2] = BFRAG(2, 0); b[3] = BFRAG(3, 0);
    SB0();
    a[1] = AFRAG(1, 0); SB0();
    a[2] = AFRAG(2, 0); SB0();
    a[3] = AFRAG(3, 0);
    stage(X, brow, ktn, 0, pn, 0);
    __builtin_amdgcn_s_barrier();
    asm volatile("s_waitcnt lgkmcnt(3)" ::: "memory"); SB0();
    __builtin_amdgcn_s_setprio(1);
    #pragma unroll
    for (int n = 0; n < 4; n++)
      acc[0][n] = __builtin_amdgcn_mfma_f32_16x16x32_bf16(a[0], b[n], acc[0][n], 0, 0, 0);
    asm volatile("s_waitcnt lgkmcnt(2)" ::: "memory"); SB0();
    #pragma unroll
    for (int n = 0; n < 4; n++)
      acc[1][n] = __builtin_amdgcn_mfma_f32_16x16x32_bf16(a[1], b[n], acc[1][n], 0, 0, 0);
    asm volatile("s_waitcnt lgkmcnt(1)" ::: "memory"); SB0();
    #pragma unroll
    for (int n = 0; n < 4; n++)
      acc[2][n] = __builtin_amdgcn_mfma_f32_16x16x32_bf16(a[2], b[n], acc[2][n], 0, 0, 0);
    asm volatile("s_waitcnt lgkmcnt(0)" ::: "memory"); SB0();
    #pragma unroll
    for (int n = 0; n < 4; n++)
      acc[3][n] = __builtin_amdgcn_mfma_f32_16x16x32_bf16(a[3], b[n], acc[3][n], 0, 0, 0);
    __builtin_amdgcn_s_setprio(0);
    __builtin_amdgcn_s_barrier();

    // ---- P2
    a[0] = AFRAG(4, 0); SB0();
    a[1] = AFRAG(5, 0); SB0();
    a[2] = AFRAG(6, 0); SB0();
    a[3] = AFRAG(7, 0);
    stage(Wgu, bcol, ktn, 0, pn, 16384);
    __builtin_amdgcn_s_barrier();
    asm volatile("s_waitcnt lgkmcnt(3)" ::: "memory"); SB0();
    __builtin_amdgcn_s_setprio(1);
    #pragma unroll
    for (int n = 0; n < 4; n++)
      acc[4][n] = __builtin_amdgcn_mfma_f32_16x16x32_bf16(a[0], b[n], acc[4][n], 0, 0, 0);
    asm volatile("s_waitcnt lgkmcnt(2)" ::: "memory"); SB0();
    #pragma unroll
    for (int n = 0; n < 4; n++)
      acc[5][n] = __builtin_amdgcn_mfma_f32_16x16x32_bf16(a[1], b[n], acc[5][n], 0, 0, 0);
    asm volatile("s_waitcnt lgkmcnt(1)" ::: "memory"); SB0();
    #pragma unroll
    for (int n = 0; n < 4; n++)
      acc[6][n] = __builtin_amdgcn_mfma_f32_16x16x32_bf16(a[2], b[n], acc[6][n], 0, 0, 0);
    asm volatile("s_waitcnt lgkmcnt(0)" ::: "memory"); SB0();
    #pragma unroll
    for (int n = 0; n < 4; n++)
      acc[7][n] = __builtin_amdgcn_mfma_f32_16x16x32_bf16(a[3], b[n], acc[7][n], 0, 0, 0);
    __builtin_amdgcn_s_setprio(0);
    asm volatile("s_waitcnt vmcnt(4)" ::: "memory");
    __builtin_amdgcn_s_barrier();

    // ---- P3
    a[0] = AFRAG(0, 1);
    b[0] = BFRAG(0, 1); b[1] = BFRAG(1, 1); b[2] = BFRAG(2, 1); b[3] = BFRAG(3, 1);
    SB0();
    a[1] = AFRAG(1, 1); SB0();
    a[2] = AFRAG(2, 1); SB0();
    a[3] = AFRAG(3, 1);
    stage(X, brow, ktn, 1, pn, 0);
    __builtin_amdgcn_s_barrier();
    asm volatile("s_waitcnt lgkmcnt(3)" ::: "memory"); SB0();
    __builtin_amdgcn_s_setprio(1);
    #pragma unroll
    for (int n = 0; n < 4; n++)
      acc[0][n] = __builtin_amdgcn_mfma_f32_16x16x32_bf16(a[0], b[n], acc[0][n], 0, 0, 0);
    asm volatile("s_waitcnt lgkmcnt(2)" ::: "memory"); SB0();
    #pragma unroll
    for (int n = 0; n < 4; n++)
      acc[1][n] = __builtin_amdgcn_mfma_f32_16x16x32_bf16(a[1], b[n], acc[1][n], 0, 0, 0);
    asm volatile("s_waitcnt lgkmcnt(1)" ::: "memory"); SB0();
    #pragma unroll
    for (int n = 0; n < 4; n++)
      acc[2][n] = __builtin_amdgcn_mfma_f32_16x16x32_bf16(a[2], b[n], acc[2][n], 0, 0, 0);
    asm volatile("s_waitcnt lgkmcnt(0)" ::: "memory"); SB0();
    #pragma unroll
    for (int n = 0; n < 4; n++)
      acc[3][n] = __builtin_amdgcn_mfma_f32_16x16x32_bf16(a[3], b[n], acc[3][n], 0, 0, 0);
    __builtin_amdgcn_s_setprio(0);
    __builtin_amdgcn_s_barrier();

    // ---- P4
    a[0] = AFRAG(4, 1); SB0();
    a[1] = AFRAG(5, 1); SB0();
    a[2] = AFRAG(6, 1); SB0();
    a[3] = AFRAG(7, 1);
    stage(Wgu, bcol, ktn, 1, pn, 16384);
    __builtin_amdgcn_s_barrier();
    asm volatile("s_waitcnt lgkmcnt(3)" ::: "memory"); SB0();
    __builtin_amdgcn_s_setprio(1);
    #pragma unroll
    for (int n = 0; n < 4; n++)
      acc[4][n] = __builtin_amdgcn_mfma_f32_16x16x32_bf16(a[0], b[n], acc[4][n], 0, 0, 0);
    asm volatile("s_waitcnt lgkmcnt(2)" ::: "memory"); SB0();
    #pragma unroll
    for (int n = 0; n < 4; n++)
      acc[5][n] = __builtin_amdgcn_mfma_f32_16x16x32_bf16(a[1], b[n], acc[5][n], 0, 0, 0);
    asm volatile("s_waitcnt lgkmcnt(1)" ::: "memory"); SB0();
    #pragma unroll
    for (int n = 0; n < 4; n++)
      acc[6][n] = __builtin_amdgcn_mfma_f32_16x16x32_bf16(a[2], b[n], acc[6][n], 0, 0, 0);
    asm volatile("s_waitcnt lgkmcnt(0)" ::: "memory"); SB0();
    #pragma unroll
    for (int n = 0; n < 4; n++)
      acc[7][n] = __builtin_amdgcn_mfma_f32_16x16x32_bf16(a[3], b[n], acc[7][n], 0, 0, 0);
    __builtin_amdgcn_s_setprio(0);
    asm volatile("s_waitcnt vmcnt(4)" ::: "memory");
    __builtin_amdgcn_s_barrier();
  }
#undef AFRAG
#undef BFRAG

  #pragma unroll
  for (int mf = 0; mf < 8; mf++)
    #pragma unroll
    for (int i = 0; i < 4; i++) {
      const long r = brow + wm * 128 + mf * 16 + (lane >> 4) * 4 + i;
      const float sw = sumw[r];
      #pragma unroll
      for (int q = 0; q < 2; q++) {
        const float g = acc[mf][2 * q][i], u = acc[mf][2 * q + 1][i];
        const int hcol = (bn * 8 + wn * 2 + q) * 16 + (lane & 15);
        hidP[r * LDP + hcol] = f2bf_bits(sw * (siluf(g) * u));
      }
    }
}

// ------------- shared 128^2 K-loop (BK=32, swizzled) ------------------------
__device__ __forceinline__ void kloop128(const u16* __restrict__ A, const u16* __restrict__ B,
                                         int lda, int ldb, int K,
                                         u16* lA, u16* lB, f32x4 (&acc)[4][4])
{
  const int tid = threadIdx.x, wave = tid >> 6, lane = tid & 63;
  const int wr = (wave >> 1) * 64, wc = (wave & 1) * 64;
  const int sr = tid >> 2, sks = ((tid & 3) ^ ((tid >> 3) & 3)) * 8;
  const u16* gA = A + (long)sr * lda + sks;
  const u16* gB = B + (long)sr * ldb + sks;
  const long rA = (long)64 * lda, rB = (long)64 * ldb;
  u16* lA0 = &lA[wave * 512]; u16* lA1 = &lA[2048 + wave * 512];
  u16* lB0 = &lB[wave * 512]; u16* lB1 = &lB[2048 + wave * 512];
  const int frow = lane & 15;
  const int fks = ((lane >> 4) * 8) ^ (((lane >> 1) & 3) << 3);

  for (int kt = 0; kt < K; kt += 32) {
    gload16(gA, lA0); gload16(gA + rA, lA1);
    gload16(gB, lB0); gload16(gB + rB, lB1);
    gA += 32; gB += 32;
    asm volatile("s_waitcnt vmcnt(0)" ::: "memory");
    __syncthreads();
    bf16x8 af[4], bfv[4];
    #pragma unroll
    for (int m = 0; m < 4; m++) af[m] = *(const bf16x8*)&lA[(wr + m * 16 + frow) * 32 + fks];
    #pragma unroll
    for (int n = 0; n < 4; n++) bfv[n] = *(const bf16x8*)&lB[(wc + n * 16 + frow) * 32 + fks];
    #pragma unroll
    for (int m = 0; m < 4; m++)
      #pragma unroll
      for (int n = 0; n < 4; n++)
        acc[m][n] = __builtin_amdgcn_mfma_f32_16x16x32_bf16(af[m], bfv[n], acc[m][n], 0, 0, 0);
    __syncthreads();
  }
}

__device__ __forceinline__ void acc_zero(f32x4 (&acc)[4][4]){
  #pragma unroll
  for (int m = 0; m < 4; m++)
    #pragma unroll
    for (int n = 0; n < 4; n++)
      #pragma unroll
      for (int i = 0; i < 4; i++) acc[m][n][i] = 0.f;
}

// ======== fused adapter v2: 16-row tiles, t=64, 2 blocks/CU =================
#define FB_AIN 0
#define FB_S   2048
#define FB_AO  3072
#define FB_AI  19456
__global__ void __launch_bounds__(256, 2)
fused_adapt(const u16* __restrict__ a_in, const u16* __restrict__ a_inT,
            const u16* __restrict__ a_out, const float* __restrict__ sumw,
            u16* __restrict__ hidP)
{
  extern __shared__ u16 lds[];
  const int tid = threadIdx.x, w = tid >> 6, lane = tid & 63;
  const int l15 = lane & 15, khi = lane >> 4;
  const int b = blockIdx.x >> 7, yt = blockIdx.x & 127;
  const int n0 = yt * 16;
  const u16* ain_b  = a_in  + (long)b * SEQ * ADIM;
  const u16* aout_b = a_out + (long)b * SEQ * ADIM;
  const u16* ainT_b = a_inT + (long)b * ADIM * SEQ;

  {
    int c = tid, row = c >> 4, slot = c & 15;
    gload16(ain_b + (long)(n0 + row) * ADIM + ((slot ^ (row & 7)) * 8),
            &lds[FB_AIN + c * 8]);
  }
  auto stage_tile = [&](int t0, int pb) {
    #pragma unroll
    for (int k = 0; k < 4; k++) {
      int c = tid + k * 256;
      int row = c >> 4, slot = c & 15;
      gload16(aout_b + (long)(t0 + row) * ADIM + ((slot ^ (row & 7)) * 8),
              &lds[FB_AO + pb * 8192 + c * 8]);
    }
    #pragma unroll
    for (int k = 0; k < 4; k++) {
      int c = tid + k * 256;
      int row = c >> 3, slot = c & 7;
      gload16(ainT_b + (long)row * SEQ + t0 + ((slot ^ (row & 7)) * 8),
              &lds[FB_AI + pb * 8192 + c * 8]);
    }
  };
  stage_tile(0, 0);

  f32x4 pacc[2];
  #pragma unroll
  for (int nf = 0; nf < 2; nf++)
    #pragma unroll
    for (int i = 0; i < 4; i++) pacc[nf][i] = 0.f;

#define LF256(base, row, kc) (*(const bf16x8*)&lds[(base) + (row)*128 + (((kc) ^ ((row)&7))*8)])
#define LF128(base, row, kc) (*(const bf16x8*)&lds[(base) + (row)*64  + (((kc) ^ ((row)&7))*8)])
#define MF(a_, b_, c_) __builtin_amdgcn_mfma_f32_16x16x32_bf16(a_, b_, c_, 0, 0, 0)

  for (int tt = 0; tt < 32; ++tt) {
    const int p = tt & 1;
    const int ttn = (tt < 31) ? tt + 1 : 31;
    stage_tile(ttn * 64, p ^ 1);
    asm volatile("s_waitcnt vmcnt(8)" ::: "memory");
    __syncthreads();

    f32x4 sacc;
    #pragma unroll
    for (int i = 0; i < 4; i++) sacc[i] = 0.f;
    const int AOb = FB_AO + p * 8192;
    #pragma unroll
    for (int ks = 0; ks < 4; ks++) {
      int kc = ks * 4 + khi;
      bf16x8 av = LF256(FB_AIN, l15, kc);
      bf16x8 bv = LF256(AOb, w * 16 + l15, kc);
      sacc = MF(av, bv, sacc);
    }
    #pragma unroll
    for (int i = 0; i < 4; i++) {
      int row = khi * 4 + i;
      int col = w * 16 + l15;
      float v = fminf(5.f, fmaxf(-5.f, sacc[i]));
      lds[FB_S + row * 64 + (((col >> 3) ^ (row & 7)) * 8) + (col & 7)] =
          f2bf_bits(siluf(v));
    }
    __syncthreads();
    const int AIb = FB_AI + p * 8192;
    #pragma unroll
    for (int ks = 0; ks < 2; ks++) {
      int kc = ks * 4 + khi;
      bf16x8 av = LF128(FB_S, l15, kc);
      #pragma unroll
      for (int nf = 0; nf < 2; nf++) {
        bf16x8 bv = LF128(AIb, w * 32 + nf * 16 + l15, kc);
        pacc[nf] = MF(av, bv, pacc[nf]);
      }
    }
    __syncthreads();
  }
#undef LF256
#undef LF128
#undef MF

  const long nb = (long)b * SEQ + n0;
  #pragma unroll
  for (int nf = 0; nf < 2; nf++)
    #pragma unroll
    for (int i = 0; i < 4; i++) {
      long n = nb + khi * 4 + i;
      int c = w * 32 + nf * 16 + l15;
      hidP[n * LDP + 2048 + c] = f2bf_bits(0.1f * sumw[n] * pacc[nf][i]);
    }
}

// ------ merged: pre-split (blk<256) | M1/M2-split (blk 256-319) -------------
__global__ void __launch_bounds__(256, 2)
split_pq(const u16* __restrict__ xb, const u16* __restrict__ Wpreb,
         const u16* __restrict__ WdQ, const u16* __restrict__ WaTb,
         const u16* __restrict__ Wob, const u16* __restrict__ WeTb,
         float* __restrict__ part, float* __restrict__ qpart)
{
  __shared__ u16 lA[4096];
  __shared__ u16 lB[4096];
  const int blk = blockIdx.x;
  const int wave = threadIdx.x >> 6, lane = threadIdx.x & 63;
  f32x4 acc[4][4]; acc_zero(acc);
  const int wr = (wave >> 1) * 64, wc = (wave & 1) * 64;

  if (blk < 256) {
    const int y = blk & 63, z = blk >> 6;
    const long brow = (long)y * 128;
    const u16* A = xb + brow * DIM + (long)z * 256;
    const u16* B = Wpreb + (long)z * 256;
    kloop128(A, B, DIM, DIM, 256, lA, lB, acc);
    float* po = part + (long)z * (N_TOK * ADIM);
    const long rr = brow + wr + ((lane >> 4) << 2);
    const int cc = wc + (lane & 15);
    #pragma unroll
    for (int m = 0; m < 4; m++)
      #pragma unroll
      for (int i = 0; i < 4; i++) {
        long r = rr + m * 16 + i;
        #pragma unroll
        for (int n = 0; n < 4; n++)
          po[r * 128 + cc + n * 16] = acc[m][n][i];
      }
  } else {
    const int q = blk - 256;
    const int y = q & 7, z = q >> 3;
    const int sel = z >> 2, split = z & 3;
    const long brow = (long)y * 128;
    const int lda = sel ? HID : LDP;
    const u16* A = (sel ? Wob : WdQ) + brow * lda + (long)split * 512;
    const u16* B = (sel ? WeTb : WaTb) + (long)split * 512;
    kloop128(A, B, lda, HID, 512, lA, lB, acc);
    float* po = qpart + (long)z * 131072;
    const long rr = brow + wr + ((lane >> 4) << 2);
    const int cc = wc + (lane & 15);
    #pragma unroll
    for (int m = 0; m < 4; m++)
      #pragma unroll
      for (int i = 0; i < 4; i++) {
        long r = rr + m * 16 + i;
        #pragma unroll
        for (int n = 0; n < 4; n++)
          po[r * 128 + cc + n * 16] = acc[m][n][i];
      }
  }
}

// ------ merged: he-GEMM (blk<512) | postf-split (blk 512-767) ---------------
__global__ void __launch_bounds__(256, 2)
he_postf(const u16* __restrict__ preb, const u16* __restrict__ Weadb,
         u16* __restrict__ heb, const u16* __restrict__ hidP,
         const u16* __restrict__ Wpostb, float* __restrict__ postfp)
{
  __shared__ u16 lA[4096];
  __shared__ u16 lB[4096];
  const int blk = blockIdx.x;
  const int wave = threadIdx.x >> 6, lane = threadIdx.x & 63;
  f32x4 acc[4][4]; acc_zero(acc);
  const int wr = (wave >> 1) * 64, wc = (wave & 1) * 64;

  if (blk < 512) {
    const int y = blk & 63, e = blk >> 6;
    const long brow = (long)y * 128;
    const u16* A = preb + brow * ADIM;
    const u16* B = Weadb + (long)e * ADIM * ADIM;
    kloop128(A, B, ADIM, ADIM, ADIM, lA, lB, acc);
    u16* O = heb + (long)e * N_TOK * ADIM;
    const long r0 = brow + wr + ((lane >> 4) << 2);
    const long c0 = wc + (lane & 15);
    #pragma unroll
    for (int m = 0; m < 4; m++)
      #pragma unroll
      for (int i = 0; i < 4; i++) {
        long r = r0 + m * 16 + i;
        #pragma unroll
        for (int n = 0; n < 4; n++)
          O[r * ADIM + c0 + n * 16] = f2bf_bits(acc[m][n][i]);
      }
  } else {
    const int q = blk - 512;
    const int y = q & 63, z = q >> 6;
    const long brow = (long)y * 128;
    const u16* A = hidP + brow * LDP + (long)z * 512;
    const u16* B = Wpostb + (long)z * 512;
    kloop128(A, B, LDP, HID, 512, lA, lB, acc);
    float* po = postfp + (long)z * (N_TOK * ADIM);
    const long rr = brow + wr + ((lane >> 4) << 2);
    const int cc = wc + (lane & 15);
    #pragma unroll
    for (int m = 0; m < 4; m++)
      #pragma unroll
      for (int i = 0; i < 4; i++) {
        long r = rr + m * 16 + i;
        #pragma unroll
        for (int n = 0; n < 4; n++)
          po[r * 128 + cc + n * 16] = acc[m][n][i];
      }
  }
}

// ------- out = hidP @ WdQ^T (K=2304) + loss; XCD row-group swizzle ----------
__global__ void __launch_bounds__(256, 2)
gemm_f32(const u16* __restrict__ Ag, const u16* __restrict__ Bg,
         const float* __restrict__ stats, float* __restrict__ out)
{
  __shared__ u16 lA[4096];
  __shared__ u16 lB[4096];
  const int wave = threadIdx.x >> 6, lane = threadIdx.x & 63;
  const int id = blockIdx.x;
  const int xcd = id & 7, k = id >> 3;
  const long brow = (long)(xcd * 8 + (k & 7)) * 128;
  const long bcol = (long)(k >> 3) * 128;
  f32x4 acc[4][4]; acc_zero(acc);
  kloop128(Ag + brow * LDP, Bg + bcol * LDP, LDP, LDP, LDP, lA, lB, acc);
  const int wr = (wave >> 1) * 64, wc = (wave & 1) * 64;
  const long r0 = brow + wr + ((lane >> 4) << 2);
  const long c0 = bcol + wc + (lane & 15);
  #pragma unroll
  for (int m = 0; m < 4; m++)
    #pragma unroll
    for (int i = 0; i < 4; i++) {
      long r = r0 + m * 16 + i;
      #pragma unroll
      for (int n = 0; n < 4; n++)
        out[r * DIM + c0 + n * 16] = acc[m][n][i];
    }
  if (id == 0 && threadIdx.x == 0) {
    float tot = 0;
    #pragma unroll
    for (int e = 0; e < 8; e++) tot += stats[e];
    float target = tot * 0.125f;
    float lb = 0;
    #pragma unroll
    for (int e = 0; e < 8; e++) { float d = stats[e] - target; lb += d * d; }
    lb *= 0.125f;
    float z = stats[8] * (1.f / (8192.f * 2.f)) + stats[9] * (1.f / (8192.f * 4.f));
    out[(size_t)N_TOK * DIM] = 0.001f * (lb + z);
  }
}

// ======== merged prep: router | wprep | cvt_t2 ==============================
__global__ void __launch_bounds__(256)
prep_all(const float* __restrict__ x, const float* __restrict__ Wrg,
         const float* __restrict__ Wre, float* __restrict__ sumw,
         float* __restrict__ fwv, int* __restrict__ eidxv,
         float* __restrict__ stats, u16* __restrict__ xb,
         const float* __restrict__ Wg, const float* __restrict__ Wu,
         const float* __restrict__ Wd, const float* __restrict__ Wo,
         const float* __restrict__ Wpost, const float* __restrict__ Wpre,
         const float* __restrict__ Wead,
         u16* __restrict__ Wgu, u16* __restrict__ WdQ,
         u16* __restrict__ Wob, u16* __restrict__ Wpostb,
         u16* __restrict__ Wpreb, u16* __restrict__ Weadb,
         const float* __restrict__ Wa, const float* __restrict__ We,
         u16* __restrict__ Ta, u16* __restrict__ Te)
{
  __shared__ float lst[10];
  const int blk = blockIdx.x;
  if (blk < 512) {
    if (threadIdx.x < 10) lst[threadIdx.x] = 0.f;
    __syncthreads();
    const int wave = threadIdx.x >> 6, lane = threadIdx.x & 63;
    const float4* wg0 = (const float4*)Wrg;
    const float4* wg1 = (const float4*)(Wrg + 1024);
    const float4* we0 = (const float4*)Wre;
    const float4* we1 = (const float4*)(Wre + 1024);
    const float4* we2 = (const float4*)(Wre + 2048);
    const float4* we3 = (const float4*)(Wre + 3072);
    for (int t = 0; t < 4; t++) {
      const long n = (long)blk * 16 + wave * 4 + t;
      const float4* xr = (const float4*)(x + n * 1024);
      float d0 = 0, d1 = 0, t0 = 0, t1 = 0, t2 = 0, t3 = 0;
      #pragma unroll
      for (int j = 0; j < 4; j++) {
        int id = j * 64 + lane;
        float4 xv = xr[id];
        ushort4 xc;
        xc.x = f2bf_bits(xv.x); xc.y = f2bf_bits(xv.y);
        xc.z = f2bf_bits(xv.z); xc.w = f2bf_bits(xv.w);
        *(ushort4*)(xb + n * 1024 + id * 4) = xc;
        float4 a;
        a = wg0[id]; d0 += xv.x * a.x + xv.y * a.y + xv.z * a.z + xv.w * a.w;
        a = wg1[id]; d1 += xv.x * a.x + xv.y * a.y + xv.z * a.z + xv.w * a.w;
        a = we0[id]; t0 += xv.x * a.x + xv.y * a.y + xv.z * a.z + xv.w * a.w;
        a = we1[id]; t1 += xv.x * a.x + xv.y * a.y + xv.z * a.z + xv.w * a.w;
        a = we2[id]; t2 += xv.x * a.x + xv.y * a.y + xv.z * a.z + xv.w * a.w;
        a = we3[id]; t3 += xv.x * a.x + xv.y * a.y + xv.z * a.z + xv.w * a.w;
      }
      #pragma unroll
      for (int o = 32; o; o >>= 1) {
        d0 += __shfl_xor(d0, o); d1 += __shfl_xor(d1, o);
        t0 += __shfl_xor(t0, o); t1 += __shfl_xor(t1, o);
        t2 += __shfl_xor(t2, o); t3 += __shfl_xor(t3, o);
      }
      if (lane == 0) {
        float mg = fmaxf(d0, d1);
        float e0 = __expf(d0 - mg), e1 = __expf(d1 - mg);
        float invg = 1.f / (e0 + e1);
        float p0 = e0 * invg, p1 = e1 * invg;
        int gi = (d1 > d0) ? 1 : 0;
        float gw = fmaxf(p0, p1);
        float l[4] = {t0, t1, t2, t3};
        float ml = fmaxf(fmaxf(l[0], l[1]), fmaxf(l[2], l[3]));
        float p[4]; float su = 0;
        #pragma unroll
        for (int i = 0; i < 4; i++) { p[i] = __expf(l[i] - ml); su += p[i]; }
        float isu = 1.f / su;
        #pragma unroll
        for (int i = 0; i < 4; i++) p[i] *= isu;
        int i1 = 0;
        #pragma unroll
        for (int i = 1; i < 4; i++) if (p[i] > p[i1]) i1 = i;
        int i2 = (i1 == 0) ? 1 : 0;
        #pragma unroll
        for (int i = 0; i < 4; i++) if (i != i1 && p[i] > p[i2]) i2 = i;
        float s2 = p[i1] + p[i2];
        float invs = 1.f / (s2 + 1e-7f);
        float f1 = gw * p[i1] * invs, f2 = gw * p[i2] * invs;
        int ea = gi * 4 + i1, eb = gi * 4 + i2;
        sumw[n] = f1 + f2;
        fwv[2 * n] = f1; fwv[2 * n + 1] = f2;
        eidxv[2 * n] = ea; eidxv[2 * n + 1] = eb;
        atomicAdd(&lst[ea], f1);
        atomicAdd(&lst[eb], f2);
        atomicAdd(&lst[8], d0 * d0 + d1 * d1);
        atomicAdd(&lst[9], t0 * t0 + t1 * t1 + t2 * t2 + t3 * t3);
      }
    }
    __syncthreads();
    if (threadIdx.x < 10) atomicAdd(&stats[threadIdx.x], lst[threadIdx.x]);
  } else if (blk < 4864) {
    long i = ((long)(blk - 512) * 256 + threadIdx.x) * 8;
    const float* s; u16* d; long so, doff;
    if (i < 4194304) {
      long rp = i >> 10, c = i & 1023;
      long i32 = rp >> 5, wi = rp & 31;
      s = (wi < 16) ? Wg : Wu;
      so = (i32 * 16 + (wi & 15)) * 1024 + c;
      d = Wgu; doff = i;
    } else if (i < 6291456) {
      long j = i - 4194304;
      long r = j >> 11, c = j & 2047;
      s = Wd; so = j;
      d = WdQ; doff = r * LDP + c;
    } else if (i < 8388608) { s = Wo;    so = i - 6291456; d = Wob;    doff = so; }
    else if (i < 8650752)   { s = Wpost; so = i - 8388608; d = Wpostb; doff = so; }
    else if (i < 8781824)   { s = Wpre;  so = i - 8650752; d = Wpreb;  doff = so; }
    else                    { s = Wead;  so = i - 8781824; d = Weadb;  doff = so; }
    float4 v0 = *(const float4*)(s + so), v1 = *(const float4*)(s + so + 4);
    ushort4 p, q;
    p.x = f2bf_bits(v0.x); p.y = f2bf_bits(v0.y); p.z = f2bf_bits(v0.z); p.w = f2bf_bits(v0.w);
    q.x = f2bf_bits(v1.x); q.y = f2bf_bits(v1.y); q.z = f2bf_bits(v1.z); q.w = f2bf_bits(v1.w);
    *(ushort4*)(d + doff) = p;
    *(ushort4*)(d + doff + 4) = q;
  } else {
    int bid = blk - 4864;
    const float* src = (bid < 1024) ? Wa : We;
    u16* dst = (bid < 1024) ? Ta : Te;
    int idx = (bid & 1023) * 256 + threadIdx.x;
    int c = idx >> 11, r = idx & 2047;
    dst[idx] = f2bf_bits(src[(long)r * 128 + c]);
  }
}

// ------ merged: ln_rows(pre) (blk<2048) | reduce_q (blk 2048-3071) ----------
__global__ void __launch_bounds__(256)
ln1_rq(const float* __restrict__ part, const float* __restrict__ qpart,
       const float* __restrict__ g, const float* __restrict__ b,
       u16* __restrict__ a_in, u16* __restrict__ a_inT, u16* __restrict__ preb,
       u16* __restrict__ WdQ)
{
  const int blk = blockIdx.x;
  if (blk < 2048) {
    int wave = threadIdx.x >> 6, lane = threadIdx.x & 63;
    long n = (long)blk * 4 + wave;
    long base = n * 128;
    float x0 = 0.f, x1 = 0.f;
    #pragma unroll
    for (int s = 0; s < 4; s++) {
      x0 += part[(long)s * (N_TOK * ADIM) + base + lane];
      x1 += part[(long)s * (N_TOK * ADIM) + base + 64 + lane];
    }
    float s2 = x0 + x1, q = x0 * x0 + x1 * x1;
    #pragma unroll
    for (int o = 32; o; o >>= 1) { s2 += __shfl_xor(s2, o); q += __shfl_xor(q, o); }
    float m = s2 * (1.f / 128.f);
    float var = q * (1.f / 128.f) - m * m;
    float inv = rsqrtf(var + 1e-5f);
    float y0 = (x0 - m) * inv * g[lane] + b[lane];
    float y1 = (x1 - m) * inv * g[lane + 64] + b[lane + 64];
    a_in[base + lane] = f2bf_bits(y0);
    a_in[base + 64 + lane] = f2bf_bits(y1);
    long bb = n >> 11, ss = n & 2047;
    a_inT[(bb * 128 + lane) * 2048 + ss] = f2bf_bits(y0);
    a_inT[(bb * 128 + lane + 64) * 2048 + ss] = f2bf_bits(y1);
    preb[base + lane] = f2bf_bits(x0);
    preb[base + 64 + lane] = f2bf_bits(x1);
  } else {
    int idx = (blk - 2048) * 256 + threadIdx.x;
    int r = idx >> 8, c = idx & 255;
    const float* p = qpart + ((c < 128) ? 0 : 524288) + (long)r * 128 + (c & 127);
    float a = p[0] + p[131072] + p[262144] + p[393216];
    WdQ[(long)r * LDP + 2048 + c] = f2bf_bits(a);
  }
}

// ------ merged: ln_combine (blk<2048) | ln_rows(postf) (blk 2048-4095) ------
__global__ void __launch_bounds__(256)
lnc_ln2(const u16* __restrict__ heb, const int* __restrict__ eidxv,
        const float* __restrict__ fwv, const float* __restrict__ g_e,
        const float* __restrict__ b_e, u16* __restrict__ hidP,
        const float* __restrict__ postfp, const float* __restrict__ g_an,
        const float* __restrict__ b_an, const float* __restrict__ sumw,
        u16* __restrict__ a_out)
{
  const int blk = blockIdx.x;
  const int wave = threadIdx.x >> 6, lane = threadIdx.x & 63;
  if (blk < 2048) {
    const long n = (long)blk * 4 + wave;
    float o0 = 0.f, o1 = 0.f;
    #pragma unroll
    for (int k = 0; k < 2; k++) {
      const int e = eidxv[2 * n + k];
      const float w = fwv[2 * n + k];
      const u16* row = heb + ((long)e * N_TOK + n) * 128;
      float h0 = bf2f(row[lane]), h1 = bf2f(row[lane + 64]);
      float s = h0 + h1, q = h0 * h0 + h1 * h1;
      #pragma unroll
      for (int o = 32; o; o >>= 1) { s += __shfl_xor(s, o); q += __shfl_xor(q, o); }
      float m = s * (1.f / 128.f);
      float var = q * (1.f / 128.f) - m * m;
      float inv = rsqrtf(var + 1e-5f);
      o0 += w * ((h0 - m) * inv * g_e[e * 128 + lane] + b_e[e * 128 + lane]);
      o1 += w * ((h1 - m) * inv * g_e[e * 128 + lane + 64] + b_e[e * 128 + lane + 64]);
    }
    hidP[n * LDP + 2176 + lane] = f2bf_bits(0.1f * o0);
    hidP[n * LDP + 2176 + 64 + lane] = f2bf_bits(0.1f * o1);
  } else {
    long n = (long)(blk - 2048) * 4 + wave;
    long base = n * 128;
    float x0 = 0.f, x1 = 0.f;
    #pragma unroll
    for (int s = 0; s < 4; s++) {
      x0 += postfp[(long)s * (N_TOK * ADIM) + base + lane];
      x1 += postfp[(long)s * (N_TOK * ADIM) + base + 64 + lane];
    }
    float invw = 1.f / sumw[n]; x0 *= invw; x1 *= invw;
    float s2 = x0 + x1, q = x0 * x0 + x1 * x1;
    #pragma unroll
    for (int o = 32; o; o >>= 1) { s2 += __shfl_xor(s2, o); q += __shfl_xor(q, o); }
    float m = s2 * (1.f / 128.f);
    float var = q * (1.f / 128.f) - m * m;
    float inv = rsqrtf(var + 1e-5f);
    a_out[base + lane] = f2bf_bits((x0 - m) * inv * g_an[lane] + b_an[lane]);
    a_out[base + 64 + lane] = f2bf_bits((x1 - m) * inv * g_an[lane + 64] + b_an[lane + 64]);
  }
}

// ----------------------------------------------------------------------------
extern "C" void kernel_launch(void* const* d_in, const int* in_sizes, int n_in,
                              void* d_out, int out_size, void* d_ws, size_t ws_size,
                              hipStream_t stream)
{
  (void)in_sizes; (void)n_in; (void)out_size; (void)ws_size;
  const float* x       = (const float*)d_in[0];
  const float* W_up    = (const float*)d_in[1];
  const float* W_gate  = (const float*)d_in[2];
  const float* W_down  = (const float*)d_in[3];
  const float* W_pre   = (const float*)d_in[4];
  const float* W_post  = (const float*)d_in[5];
  const float* g_an    = (const float*)d_in[6];
  const float* b_an    = (const float*)d_in[7];
  const float* W_aproj = (const float*)d_in[8];
  const float* W_ead   = (const float*)d_in[9];
  const float* g_e     = (const float*)d_in[10];
  const float* b_e     = (const float*)d_in[11];
  const float* W_eproj = (const float*)d_in[12];
  const float* W_oproj = (const float*)d_in[13];
  const float* W_rg    = (const float*)d_in[14];
  const float* W_re    = (const float*)d_in[15];
  float* out = (float*)d_out;

  char* base = (char*)d_ws; size_t off = 0;
  auto alloc = [&](size_t bytes) -> void* {
    void* p = base + off; off = (off + bytes + 255) & ~(size_t)255; return p;
  };
  u16*   xb     = (u16*)  alloc((size_t)N_TOK * DIM * 2);
  u16*   Wgu    = (u16*)  alloc((size_t)2 * HID * DIM * 2);       // packed gate|up
  u16*   WdQ    = (u16*)  alloc((size_t)DIM * LDP * 2);           // Wd | M2 | M1
  u16*   Wob    = (u16*)  alloc((size_t)DIM * HID * 2);
  u16*   Wpostb = (u16*)  alloc((size_t)ADIM * HID * 2);
  u16*   Wpreb  = (u16*)  alloc((size_t)ADIM * DIM * 2);
  u16*   WaTb   = (u16*)  alloc((size_t)ADIM * HID * 2);
  u16*   WeTb   = (u16*)  alloc((size_t)ADIM * HID * 2);
  u16*   Weadb  = (u16*)  alloc((size_t)8 * ADIM * ADIM * 2);
  u16*   hidP   = (u16*)  alloc((size_t)N_TOK * LDP * 2);         // scaled hid | P
  u16*   heb    = (u16*)  alloc((size_t)8 * N_TOK * ADIM * 2);    // also part arena
  float* part   = (float*)heb;
  u16*   preb   = (u16*)  alloc((size_t)N_TOK * ADIM * 2);
  u16*   a_in   = (u16*)  alloc((size_t)N_TOK * ADIM * 2);
  u16*   a_inT  = (u16*)  alloc((size_t)N_TOK * ADIM * 2);
  u16*   a_out  = (u16*)  alloc((size_t)N_TOK * ADIM * 2);
  float* sumw   = (float*)alloc((size_t)N_TOK * 4);
  float* fwv    = (float*)alloc((size_t)N_TOK * 2 * 4);
  int*   eidxv  = (int*)  alloc((size_t)N_TOK * 2 * 4);
  float* stats  = (float*)alloc(64);
  // d_out (33.5 MB) time-shared as scratch, all strictly before gemm_f32:
  //  - postfp (16.8 MB f32 postf partials): he_postf -> lnc_ln2
  //  - qpart  (4.2 MB f32 M1/M2 partials, at +16.8MB): split_pq -> ln1_rq
  float* postfp = (float*)d_out;
  float* qpart  = (float*)((char*)d_out + 16777216);

  hipFuncSetAttribute((const void*)gemm_gu256,
                      hipFuncAttributeMaxDynamicSharedMemorySize, 131072);
  hipFuncSetAttribute((const void*)fused_adapt,
                      hipFuncAttributeMaxDynamicSharedMemorySize, 71680);

  hipMemsetAsync(stats, 0, 64, stream);

  // 1. router | weight-pack | transposes
  prep_all<<<6912, 256, 0, stream>>>(x, W_rg, W_re, sumw, fwv, eidxv, stats, xb,
                                     W_gate, W_up, W_down, W_oproj, W_post, W_pre,
                                     W_ead, Wgu, WdQ, Wob, Wpostb, Wpreb, Weadb,
                                     W_aproj, W_eproj, WaTb, WeTb);

  // 2. hidP[:, :2048] = sumw * silu(x@Wg^T) * (x@Wu^T)
  gemm_gu256<<<512, 512, 131072, stream>>>(xb, Wgu, sumw, hidP);

  // 3. pre-split (part) | M1/M2-split (qpart)
  split_pq<<<320, 256, 0, stream>>>(xb, Wpreb, WdQ, WaTb, Wob, WeTb, part, qpart);

  // 4. LN(pre) -> a_in/a_inT/preb | reduce qpart -> WdQ Q-cols
  ln1_rq<<<3072, 256, 0, stream>>>(part, qpart, g_an, b_an, a_in, a_inT, preb, WdQ);

  // 5. he[e] = preb @ Wead[e]^T -> heb | postf-split -> postfp
  he_postf<<<768, 256, 0, stream>>>(preb, Weadb, heb, hidP, Wpostb, postfp);

  // 6. expert LN+combine -> hidP[:,2176:] | LN(postf/sumw) -> a_out
  lnc_ln2<<<4096, 256, 0, stream>>>(heb, eidxv, fwv, g_e, b_e, hidP,
                                    postfp, g_an, b_an, sumw, a_out);

  // 7. fused adapter: hidP[:,2048:2176] = 0.1*sumw*(silu(a_in@a_out^T)@a_in)
  fused_adapt<<<512, 256, 71680, stream>>>(a_in, a_inT, a_out, sumw, hidP);

  // 8. out = hidP @ WdQ^T (K=2304) + router loss
  gemm_f32<<<512, 256, 0, stream>>>(hidP, WdQ, stats, out);
}